// Round 7
// baseline (1069.478 us; speedup 1.0000x reference)
//
#include <hip/hip_runtime.h>
#include <stdint.h>

#define NN 8192
#define DD 64

// =====================================================================
// K1: k_pre — 64-row tile: transpose x -> xT (if ws allows) + squared norms.
// sq chain MUST match the k_cand dot chain so that d_ii == 0 exactly.
// =====================================================================
__global__ __launch_bounds__(256) void k_pre(const float* __restrict__ x, float* __restrict__ xT,
                                             float* __restrict__ sq, int do_tr){
  __shared__ float tile[64*65];
  const int tid = threadIdx.x;
  const int b = blockIdx.x;
  for (int k = 0; k < 4; ++k){
    const int idx4 = tid + k*256;
    const float4 v = ((const float4*)(x + (size_t)b*4096))[idx4];
    const int row = idx4 >> 4, d0 = (idx4 & 15) * 4;
    tile[row*65 + d0 + 0] = v.x;
    tile[row*65 + d0 + 1] = v.y;
    tile[row*65 + d0 + 2] = v.z;
    tile[row*65 + d0 + 3] = v.w;
  }
  __syncthreads();
  if (do_tr){
    const int jj = tid & 15;
    const int dq = tid >> 4;
    for (int k = 0; k < 4; ++k){
      const int d = dq + 16*k;
      float4 o;
      o.x = tile[(jj*4+0)*65 + d];
      o.y = tile[(jj*4+1)*65 + d];
      o.z = tile[(jj*4+2)*65 + d];
      o.w = tile[(jj*4+3)*65 + d];
      ((float4*)xT)[(size_t)d*2048 + b*16 + jj] = o;
    }
  }
  if (tid < 64){
    float acc = 0.f;
    const float* rp = tile + tid*65;
    for (int d = 0; d < 64; ++d) acc = fmaf(rp[d], rp[d], acc);
    sq[b*64 + tid] = acc;
  }
}

// =====================================================================
// K2: k_cand — unchanged (bit-exact kNN/KDE path).
// =====================================================================
template<bool XT>
__device__ __forceinline__ void dists_1024(const float* __restrict__ x, const float* __restrict__ xT,
                                           const float* __restrict__ xi, int jbase, int tid,
                                           float acc[8][4]){
#pragma unroll
  for (int r = 0; r < 8; ++r)
#pragma unroll
    for (int q = 0; q < 4; ++q) acc[r][q] = 0.f;
  const int j0 = jbase + tid*4;
  for (int dq = 0; dq < 16; ++dq){
    float4 vj[4];
    if (XT){
#pragma unroll
      for (int s = 0; s < 4; ++s)
        vj[s] = ((const float4*)xT)[(size_t)(dq*4+s)*2048 + (j0 >> 2)];
    } else {
#pragma unroll
      for (int s = 0; s < 4; ++s){
        const int d = dq*4 + s;
        vj[s].x = x[(size_t)(j0+0)*64 + d];
        vj[s].y = x[(size_t)(j0+1)*64 + d];
        vj[s].z = x[(size_t)(j0+2)*64 + d];
        vj[s].w = x[(size_t)(j0+3)*64 + d];
      }
    }
#pragma unroll
    for (int r = 0; r < 8; ++r){
      const float4 wv = ((const float4*)(xi + r*64))[dq];
      acc[r][0] = fmaf(vj[0].x, wv.x, acc[r][0]);
      acc[r][1] = fmaf(vj[0].y, wv.x, acc[r][1]);
      acc[r][2] = fmaf(vj[0].z, wv.x, acc[r][2]);
      acc[r][3] = fmaf(vj[0].w, wv.x, acc[r][3]);
      acc[r][0] = fmaf(vj[1].x, wv.y, acc[r][0]);
      acc[r][1] = fmaf(vj[1].y, wv.y, acc[r][1]);
      acc[r][2] = fmaf(vj[1].z, wv.y, acc[r][2]);
      acc[r][3] = fmaf(vj[1].w, wv.y, acc[r][3]);
      acc[r][0] = fmaf(vj[2].x, wv.z, acc[r][0]);
      acc[r][1] = fmaf(vj[2].y, wv.z, acc[r][1]);
      acc[r][2] = fmaf(vj[2].z, wv.z, acc[r][2]);
      acc[r][3] = fmaf(vj[2].w, wv.z, acc[r][3]);
      acc[r][0] = fmaf(vj[3].x, wv.w, acc[r][0]);
      acc[r][1] = fmaf(vj[3].y, wv.w, acc[r][1]);
      acc[r][2] = fmaf(vj[3].z, wv.w, acc[r][2]);
      acc[r][3] = fmaf(vj[3].w, wv.w, acc[r][3]);
    }
  }
}

template<bool XT>
__global__ __launch_bounds__(256) void k_cand(const float* __restrict__ x, const float* __restrict__ xT,
                                              const float* __restrict__ sq,
                                              float* __restrict__ res, unsigned short* __restrict__ nn16){
  __shared__ float xi[8*64];
  __shared__ float sqi_s[8];
  __shared__ float tubs[8];
  __shared__ __align__(16) unsigned long long cand[8*512];
  __shared__ unsigned ccnt[8];
  float* samp = (float*)cand;
  const int tid = threadIdx.x;
  const int i0 = blockIdx.x * 8;
  for (int t = tid; t < 8*64; t += 256) xi[t] = x[(size_t)i0*64 + t];
  if (tid < 8){ sqi_s[tid] = sq[i0+tid]; ccnt[tid] = 0u; }
  __syncthreads();
  float sqir[8];
#pragma unroll
  for (int r = 0; r < 8; ++r) sqir[r] = sqi_s[r];

  const int w0 = (blockIdx.x * 1024) & 8191;
  {
    float acc[8][4];
    dists_1024<XT>(x, xT, xi, w0, tid, acc);
    float sqj[4];
#pragma unroll
    for (int q = 0; q < 4; ++q) sqj[q] = sq[w0 + tid*4 + q];
#pragma unroll
    for (int r = 0; r < 8; ++r)
#pragma unroll
      for (int q = 0; q < 4; ++q)
        samp[r*1024 + tid*4 + q] = (sqir[r] + sqj[q]) - 2.f*acc[r][q];
  }
  __syncthreads();
  {
    const int wv = tid >> 6, lane = tid & 63;
    for (int rr = 0; rr < 2; ++rr){
      const int r = wv + rr*4;
      float v[16];
#pragma unroll
      for (int k2 = 0; k2 < 16; ++k2) v[k2] = samp[r*1024 + lane + 64*k2];
      unsigned lo = 0u, hi = 0x7F800001u;
      while (hi - lo > 1u){
        const unsigned mid = (lo + hi) >> 1;
        const float pf = __uint_as_float(mid);
        int c = 0;
#pragma unroll
        for (int k2 = 0; k2 < 16; ++k2) c += (v[k2] < pf) ? 1 : 0;
#pragma unroll
        for (int off = 32; off; off >>= 1) c += __shfl_xor(c, off);
        if (c >= 32) hi = mid; else lo = mid;
      }
      if (lane == 0) tubs[r] = __uint_as_float(hi);
    }
  }
  __syncthreads();
  float tubr[8];
#pragma unroll
  for (int r = 0; r < 8; ++r) tubr[r] = tubs[r];
  for (int t = tid; t < 8*512; t += 256) cand[t] = ~0ULL;
  __syncthreads();

  for (int pass = 0; pass < 8; ++pass){
    const int jb = pass*1024;
    float acc[8][4];
    dists_1024<XT>(x, xT, xi, jb, tid, acc);
    const int j0 = jb + tid*4;
    float sqj[4];
#pragma unroll
    for (int q = 0; q < 4; ++q) sqj[q] = sq[j0 + q];
#pragma unroll
    for (int r = 0; r < 8; ++r){
#pragma unroll
      for (int q = 0; q < 4; ++q){
        const float dist = (sqir[r] + sqj[q]) - 2.f*acc[r][q];
        if (dist < tubr[r]){
          const unsigned pos = atomicAdd(&ccnt[r], 1u);
          if (pos < 512u){
            unsigned u = __float_as_uint(dist);
            u = ((int)u < 0) ? ~u : (u | 0x80000000u);
            cand[r*512 + pos] = (((unsigned long long)u) << 13) | (unsigned)(j0 + q);
          }
        }
      }
    }
  }
  __syncthreads();

  for (int k = 2; k <= 512; k <<= 1){
    for (int jj2 = k >> 1; jj2 > 0; jj2 >>= 1){
      const int mm = tid;
      const int i = ((mm & ~(jj2-1)) << 1) | (mm & (jj2-1));
      const int p = i | jj2;
      const bool up2 = ((i & k) == 0);
#pragma unroll
      for (int r = 0; r < 8; ++r){
        unsigned long long a = cand[r*512+i], bb = cand[r*512+p];
        if ((a > bb) == up2){ cand[r*512+i] = bb; cand[r*512+p] = a; }
      }
      __syncthreads();
    }
  }

  const int wv2 = tid >> 6, lane2 = tid & 63;
  for (int rr = 0; rr < 2; ++rr){
    const int r = wv2*2 + rr;
    const unsigned long long kk = cand[r*512 + lane2];
    float e = 0.f;
    if (lane2 < 50){
      unsigned u2 = (unsigned)(kk >> 13);
      u2 = (u2 & 0x80000000u) ? (u2 & 0x7FFFFFFFu) : ~u2;
      e = expf(-__uint_as_float(u2) / 30.f);
    }
#pragma unroll
    for (int off = 32; off; off >>= 1) e += __shfl_down(e, off);
    if (lane2 == 0) res[i0+r] = e / 1500.f;
    if (lane2 < 16) nn16[(size_t)(i0+r)*16 + lane2] = (unsigned short)(kk & 8191ULL);
  }
}

__device__ __forceinline__ unsigned long long shfl64_xor(unsigned long long v, int off){
  return (((unsigned long long)(unsigned)__shfl_xor((int)(v >> 32), off)) << 32)
       | (unsigned long long)(unsigned)__shfl_xor((int)(v & 0xFFFFFFFFu), off);
}

// =====================================================================
// K3: k_suf — sort + peak-compacted Boruvka MSF + replay + loss.
// Same verified algorithm as round 6; instruction-count optimizations:
// peaks renumbered to dense ids (Boruvka arrays O(Npk) not O(NN)),
// wave-aggregated appends (1 atomic/wave), per-round edge compaction
// (ping-pong global lists), compacted loss selection (2-barrier reduces).
// =====================================================================
__global__ __launch_bounds__(1024) void k_suf(const float* __restrict__ res,
                                              const unsigned short* __restrict__ nn16,
                                              unsigned short* __restrict__ ups_t,
                                              unsigned long long* __restrict__ edges,
                                              int edgecap,
                                              float* __restrict__ out){
  __shared__ __align__(16) unsigned long long keys[NN]; // 64KB; repurposed below
  __shared__ __align__(16) unsigned short comp[NN];     // 16KB: rankv, then UF comp
  __shared__ __align__(16) unsigned short death[NN];    // 16KB
  __shared__ __align__(16) unsigned bestv[4096];        // 16KB; -> dlist at loss
  __shared__ __align__(16) unsigned long long msf[4096];// 32KB
  __shared__ __align__(16) unsigned short pkrank[4096]; // 8KB
  __shared__ unsigned scan1[1024];                      // 4KB; aliased as red (float)
  __shared__ unsigned long long wred[17];
  __shared__ unsigned long long sel[10];
  __shared__ unsigned ecnt_s, ecnt2_s, mcnt_s, chg_s, flat_s, dcnt_s;

  float*          dens = (float*)keys;                   // [0,32KB)
  unsigned short* P    = (unsigned short*)keys + 16384;  // [32KB,48KB)
  unsigned short* pkid = (unsigned short*)keys + 24576;  // [48KB,64KB), dead after B1
  unsigned short* hook = (unsigned short*)keys + 24576;  // same region, live in B2
  float* red = (float*)scan1;

  const int tid = threadIdx.x;
  const int lane = tid & 63;

  // ---- A0: max(res) ----
  float m = 0.f;
  for (int t = tid; t < NN; t += 1024) m = fmaxf(m, res[t]);
  red[tid] = m; __syncthreads();
  for (int o = 512; o; o >>= 1){ if (tid < o) red[tid] = fmaxf(red[tid], red[tid+o]); __syncthreads(); }
  const float mr = red[0];
  __syncthreads();

  // ---- A1: stable bitonic argsort (bit-exact vs prior rounds) ----
  for (int t = tid; t < NN; t += 1024){
    const float dnv = res[t] / mr;
    keys[t] = (((unsigned long long)__float_as_uint(dnv)) << 13) | (unsigned)t;
  }
  __syncthreads();
  for (int k = 2; k <= NN; k <<= 1){
    for (int j = k >> 1; j > 0; j >>= 1){
      for (int m2 = tid; m2 < NN/2; m2 += 1024){
        const int i = ((m2 & ~(j-1)) << 1) | (m2 & (j-1));
        const int p = i | j;
        const bool up = ((i & k) == 0);
        unsigned long long a = keys[i], b = keys[p];
        if ((a > b) == up){ keys[i] = b; keys[p] = a; }
      }
      __syncthreads();
    }
  }
  // ---- A2: rank inverse ----
  for (int t = tid; t < NN; t += 1024)
    comp[(unsigned)(keys[t] & 8191ULL)] = (unsigned short)t;
  __syncthreads();

  // ---- A3: ups lists (desc-sorted) + stage dens/umax in regs ----
  float dreg[8];
  unsigned short o0reg[8];
  for (int pp = 0; pp < 8; ++pp){
    const int p = tid + pp*1024;
    const unsigned long long kk = keys[p];
    dreg[pp] = __uint_as_float((unsigned)(kk >> 13));
    const unsigned orig = (unsigned)(kk & 8191ULL);
    const uint4 n0 = ((const uint4*)nn16)[(size_t)orig*2];
    const uint4 n1 = ((const uint4*)nn16)[(size_t)orig*2 + 1];
    unsigned nw[8] = {n0.x, n0.y, n0.z, n0.w, n1.x, n1.y, n1.z, n1.w};
    unsigned short outv[16];
    int cnt = 0;
    for (int k = 0; k < 16; ++k){
      const unsigned nb = (nw[k >> 1] >> ((k & 1) * 16)) & 0xFFFFu;
      const unsigned r = comp[nb];
      if ((int)r > p){
        int q = cnt++;
        while (q > 0 && outv[q-1] < (unsigned short)r){ outv[q] = outv[q-1]; --q; }
        outv[q] = (unsigned short)r;
      }
    }
    for (int k = cnt; k < 16; ++k) outv[k] = 0;
    o0reg[pp] = outv[0];
    unsigned short* dst = ups_t + (size_t)p*16;
    uint4 a, b;
    a.x = (unsigned)outv[0] | ((unsigned)outv[1] << 16);
    a.y = (unsigned)outv[2] | ((unsigned)outv[3] << 16);
    a.z = (unsigned)outv[4] | ((unsigned)outv[5] << 16);
    a.w = (unsigned)outv[6] | ((unsigned)outv[7] << 16);
    b.x = (unsigned)outv[8] | ((unsigned)outv[9] << 16);
    b.y = (unsigned)outv[10] | ((unsigned)outv[11] << 16);
    b.z = (unsigned)outv[12] | ((unsigned)outv[13] << 16);
    b.w = (unsigned)outv[14] | ((unsigned)outv[15] << 16);
    ((uint4*)dst)[0] = a;
    ((uint4*)dst)[1] = b;
  }
  __syncthreads();   // keys/comp reads done; safe to repurpose

  // ---- A4: dens/P/death init ----
  for (int pp = 0; pp < 8; ++pp){
    const int p = tid + pp*1024;
    dens[p] = dreg[pp];
    P[p] = (o0reg[pp] == 0) ? (unsigned short)p : o0reg[pp];
    death[p] = 0xFFFFu;
  }
  if (tid == 0){ ecnt_s = 0u; mcnt_s = 0u; dcnt_s = 0u; }
  __syncthreads();

  // ---- A5: pointer jumping -> P = u_max forest root (races benign) ----
  for (int rd = 0; rd < 13; ++rd){
    for (int pp = 0; pp < 8; ++pp){
      const int p = tid + pp*1024;
      const unsigned v = P[p];
      const unsigned w2 = P[v];
      if (w2 != v) P[p] = (unsigned short)w2;
    }
    __syncthreads();
  }

  // ---- A5b: peak compaction (dense ids, ascending rank) ----
  {
    const int p0 = tid*8;
    int c = 0;
    for (int k = 0; k < 8; ++k) c += (P[p0+k] == (unsigned short)(p0+k)) ? 1 : 0;
    scan1[tid] = (unsigned)c; __syncthreads();
    for (int s = 1; s < 1024; s <<= 1){
      const unsigned v = scan1[tid];
      const unsigned u = (tid >= s) ? scan1[tid-s] : 0u;
      __syncthreads();
      scan1[tid] = v + u;
      __syncthreads();
    }
    int base = (int)scan1[tid] - c;
    for (int k = 0; k < 8; ++k){
      const int p = p0 + k;
      if (P[p] == (unsigned short)p){
        pkid[p] = (unsigned short)base;
        if (base < 4096) pkrank[base] = (unsigned short)p;
        ++base;
      }
    }
  }
  __syncthreads();
  int Npk = (int)scan1[1023];
  if (Npk > 4096) Npk = 4096;
  __syncthreads();

  // ---- B1: build compact-id edge list (wave-aggregated append) ----
  for (int pp = 0; pp < 8; ++pp){
    const int p = tid + pp*1024;
    const uint4 a4 = ((const uint4*)ups_t)[(size_t)p*2];
    const uint4 b4 = ((const uint4*)ups_t)[(size_t)p*2 + 1];
    unsigned uu[8] = {a4.x, a4.y, a4.z, a4.w, b4.x, b4.y, b4.z, b4.w};
    unsigned edv[15];
    int nd = 0;
    const unsigned u0 = uu[0] & 0xFFFFu;
    if (u0 != 0u){
      const unsigned m0 = P[u0];
      const unsigned m0id = pkid[m0];
      for (int k = 1; k < 16; ++k){
        const unsigned uk = (uu[k >> 1] >> ((k & 1) * 16)) & 0xFFFFu;
        if (uk == 0u) break;
        const unsigned v = P[uk];
        if (v == m0) continue;
        const unsigned vid = pkid[v];
        bool dup = false;
        for (int j = 0; j < nd; ++j) dup = dup || ((edv[j] >> 16) == vid);
        if (dup) continue;
        edv[nd++] = (vid << 16) | m0id;
      }
    }
    unsigned off = (unsigned)nd;
    for (int s = 1; s < 64; s <<= 1){
      const unsigned o = (unsigned)__shfl_up((int)off, s);
      if (lane >= s) off += o;
    }
    const unsigned tot = (unsigned)__shfl((int)off, 63);
    unsigned wb = 0u;
    if (lane == 0 && tot) wb = atomicAdd(&ecnt_s, tot);
    wb = (unsigned)__shfl((int)wb, 0);
    const unsigned mybase = wb + off - (unsigned)nd;
    for (int k = 0; k < nd; ++k){
      const unsigned pos = mybase + (unsigned)k;
      if ((int)pos < edgecap)
        edges[pos] = (((unsigned long long)(unsigned)p) << 32) | (unsigned long long)edv[k];
    }
  }
  __syncthreads();
  int Ecur = ((int)ecnt_s < edgecap) ? (int)ecnt_s : edgecap;

  // ---- B2: Boruvka MSF over compact peak graph, edge compaction/round ----
  unsigned long long* eb_in  = edges;
  unsigned long long* eb_out = (unsigned long long*)ups_t;   // dead after B1
  for (int t = tid; t < Npk; t += 1024) comp[t] = (unsigned short)t;
  __syncthreads();
  for (int round = 0; round < 16 && Ecur > 0; ++round){
    for (int t = tid; t < Npk; t += 1024){ bestv[t] = 0u; hook[t] = 0xFFFFu; }
    if (tid == 0){ chg_s = 0u; ecnt2_s = 0u; }
    __syncthreads();
    // scan edges: mark bests + compact cross-component edges to eb_out
    for (int base = 0; base < Ecur; base += 1024){
      const int e = base + tid;
      bool keep = false;
      unsigned long long ed = 0ULL;
      if (e < Ecur){
        ed = eb_in[e];
        const unsigned a = (unsigned)(ed >> 16) & 0xFFFFu;
        const unsigned b = (unsigned)ed & 0xFFFFu;
        const unsigned ra = comp[a], rb = comp[b];
        if (ra != rb){
          keep = true;
          const unsigned key = ((((unsigned)(ed >> 32)) + 1u) << 18) | (unsigned)e;
          atomicMax(&bestv[ra], key);
          atomicMax(&bestv[rb], key);
        }
      }
      const unsigned long long bal = __ballot(keep);
      const unsigned cnt = (unsigned)__popcll(bal);
      const unsigned pfx = (unsigned)__popcll(bal & ((1ULL << lane) - 1ULL));
      unsigned wb = 0u;
      if (lane == 0 && cnt) wb = atomicAdd(&ecnt2_s, cnt);
      wb = (unsigned)__shfl((int)wb, 0);
      if (keep && (wb + pfx) < 32768u) eb_out[wb + pfx] = ed;
    }
    __syncthreads();
    // choose: each live root picks its best edge
    for (int t = tid; t < Npk; t += 1024){
      if (comp[t] == (unsigned short)t && bestv[t] != 0u){
        const unsigned long long ed = eb_in[bestv[t] & 0x3FFFFu];
        const unsigned a = (unsigned)(ed >> 16) & 0xFFFFu;
        const unsigned b = (unsigned)ed & 0xFFFFu;
        const unsigned ra = comp[a], rb = comp[b];
        hook[t] = (unsigned short)((ra == (unsigned)t) ? rb : ra);
      }
    }
    __syncthreads();
    // apply hooks (mutual pair: larger id applies) + append MSF edge
    for (int t = tid; t < Npk; t += 1024){
      const unsigned o = hook[t];
      if (o != 0xFFFFu && !(hook[o] == (unsigned short)t && (unsigned)t < o)){
        comp[t] = (unsigned short)o;
        chg_s = 1u;
        const unsigned long long ed = eb_in[bestv[t] & 0x3FFFFu];
        const unsigned pos = atomicAdd(&mcnt_s, 1u);
        if (pos < 4096u) msf[pos] = (((ed >> 32) + 1ULL) << 32) | (ed & 0xFFFFFFFFULL);
      }
    }
    __syncthreads();
    // flatten comp (over Npk)
    for (;;){
      if (tid == 0) flat_s = 0u;
      __syncthreads();
      for (int t = tid; t < Npk; t += 1024){
        const unsigned c = comp[t];
        const unsigned cc = comp[c];
        if (cc != c){ comp[t] = (unsigned short)cc; flat_s = 1u; }
      }
      __syncthreads();
      if (flat_s == 0u) break;
    }
    const int En = ((int)ecnt2_s < 32768) ? (int)ecnt2_s : 32767;
    const unsigned ch = chg_s;
    __syncthreads();
    Ecur = En;
    { unsigned long long* t2 = eb_in; eb_in = eb_out; eb_out = t2; }
    if (ch == 0u) break;
  }

  // ---- B3: sort MSF edges descending (width = pow2 >= M) ----
  const int M = ((int)mcnt_s < 4096) ? (int)mcnt_s : 4095;
  int W = 64; while (W < M) W <<= 1;
  for (int t = M + tid; t < W; t += 1024) msf[t] = 0ULL;
  for (int t = tid; t < Npk; t += 1024) comp[t] = (unsigned short)t;  // reset for replay
  __syncthreads();
  for (int k = 2; k <= W; k <<= 1){
    for (int j = k >> 1; j > 0; j >>= 1){
      for (int m2 = tid; m2 < W/2; m2 += 1024){
        const int i = ((m2 & ~(j-1)) << 1) | (m2 & (j-1));
        const int p = i | j;
        const bool up = ((i & k) == 0);
        const unsigned long long a = msf[i], b = msf[p];
        if ((a < b) == up){ msf[i] = b; msf[p] = a; }   // descending
      }
      __syncthreads();
    }
  }

  // ---- B4: sequential replay (M ~ #peaks, forest => every edge unions) ----
  if (tid == 0){
    for (int i = 0; i < M; ++i){
      const unsigned long long e = msf[i];
      const unsigned a = ((unsigned)e >> 16) & 0xFFFFu;
      const unsigned b = (unsigned)e & 0xFFFFu;
      unsigned ra = a;
      for (;;){ const unsigned c = comp[ra]; if (c == ra) break;
                const unsigned cc = comp[c]; comp[ra] = (unsigned short)cc; ra = cc; }
      unsigned rb = b;
      for (;;){ const unsigned c = comp[rb]; if (c == rb) break;
                const unsigned cc = comp[c]; comp[rb] = (unsigned short)cc; rb = cc; }
      if (ra != rb){
        death[pkrank[ra]] = (unsigned short)((unsigned)(e >> 32) - 1u);
        comp[ra] = (unsigned short)rb;
      }
    }
  }
  __syncthreads();

  // ---- A8a: S (identical strided order -> bit-exact) ----
  float s = 0.f;
  for (int e = tid; e < NN; e += 1024){
    const int dr = death[e];
    if (dr != 0xFFFF) s += dens[e] - dens[dr];
  }
  red[tid] = s; __syncthreads();
  for (int o = 512; o; o >>= 1){ if (tid < o) red[tid] += red[tid+o]; __syncthreads(); }
  const float S = red[0];

  // ---- A8b: compact death list (order-free exact selection) ----
  unsigned* dlist = bestv;   // dead after B2
  for (int e8 = 0; e8 < 8; ++e8){
    const int e = tid + e8*1024;
    const int dr = death[e];
    const bool have = (dr != 0xFFFF);
    const unsigned long long bal = __ballot(have);
    const unsigned cnt = (unsigned)__popcll(bal);
    const unsigned pfx = (unsigned)__popcll(bal & ((1ULL << lane) - 1ULL));
    unsigned wb = 0u;
    if (lane == 0 && cnt) wb = atomicAdd(&dcnt_s, cnt);
    wb = (unsigned)__shfl((int)wb, 0);
    if (have && (wb + pfx) < 4096u) dlist[wb + pfx] = ((unsigned)e << 13) | (unsigned)dr;
  }
  __syncthreads();
  const int Dm = ((int)dcnt_s < 4096) ? (int)dcnt_s : 4096;

  // ---- A8c: top-10 selection (max over distinct keys: order-free, exact) ----
  unsigned long long last = ~0ULL;
  for (int t10 = 0; t10 < 10; ++t10){
    unsigned long long km = 0ULL;
    for (int i = tid; i < Dm; i += 1024){
      const unsigned pk = dlist[i];
      const unsigned e = pk >> 13, dr = pk & 8191u;
      const float pers = dens[e] - dens[dr];
      const unsigned long long k = (((unsigned long long)__float_as_uint(pers)) << 13) | e;
      if (k < last && k > km) km = k;
    }
    for (int off = 32; off; off >>= 1){
      const unsigned long long o = shfl64_xor(km, off);
      km = (o > km) ? o : km;
    }
    if (lane == 0) wred[tid >> 6] = km;
    __syncthreads();
    if (tid < 64){
      unsigned long long v = (tid < 16) ? wred[tid] : 0ULL;
      for (int off = 8; off; off >>= 1){
        const unsigned long long o = shfl64_xor(v, off);
        v = (o > v) ? o : v;
      }
      if (tid == 0) wred[16] = v;
    }
    __syncthreads();
    const unsigned long long st = wred[16];
    if (tid == 0) sel[t10] = st;
    last = st;
    __syncthreads();
  }
  if (tid == 0){
    float top = 0.f;
    for (int t10 = 0; t10 < 10; ++t10)
      if (sel[t10]) top += __uint_as_float((unsigned)(sel[t10] >> 13));
    float strong = 0.f, dest0 = 0.f, dest1 = 0.f;
    if (sel[0]){
      const unsigned e0 = (unsigned)(sel[0] & 8191ULL);
      dest0 = dens[e0]; dest1 = dens[death[e0]];
    }
    for (int t10 = 1; t10 < 10; ++t10){
      if (!sel[t10]) continue;
      const unsigned e = (unsigned)(sel[t10] & 8191ULL);
      const float a = dens[e] - dest0;
      const float b = dens[death[e]] - dest1;
      strong += sqrtf(a*a + b*b);
    }
    out[0] = (S - top) / 1.41421356237309515f + strong;
  }
}

// =====================================================================
// launch — 3 dispatches
// =====================================================================
extern "C" void kernel_launch(void* const* d_in, const int* in_sizes, int n_in,
                              void* d_out, int out_size, void* d_ws, size_t ws_size,
                              hipStream_t stream){
  const float* x = (const float*)d_in[0];
  char* w = (char*)d_ws;
  float*          sq     = (float*)(w + 0);                 // 32KB
  float*          res    = (float*)(w + 32768);             // 32KB
  unsigned short* nn16   = (unsigned short*)(w + 65536);    // 256KB
  unsigned short* ups_t  = (unsigned short*)(w + 327680);   // 256KB (edge ping-pong in B2)
  float*          xT     = (float*)(w + 589824);            // 2MB (optional)
  const int use_xt = (ws_size >= (size_t)(589824 + NN*DD*4)) ? 1 : 0;
  unsigned long long* edges = use_xt ? (unsigned long long*)(w + 589824)
                                     : (unsigned long long*)(w + 65536);
  const int edgecap = use_xt ? 262143 : 32767;

  k_pre<<<128, 256, 0, stream>>>(x, xT, sq, use_xt);
  if (use_xt) k_cand<true ><<<1024, 256, 0, stream>>>(x, xT, sq, res, nn16);
  else        k_cand<false><<<1024, 256, 0, stream>>>(x, xT, sq, res, nn16);
  k_suf<<<1, 1024, 0, stream>>>(res, nn16, ups_t, edges, edgecap, (float*)d_out);
}

// Round 8
// 1032.452 us; speedup vs baseline: 1.0359x; 1.0359x over previous
//
#include <hip/hip_runtime.h>
#include <stdint.h>

#define NN 8192
#define DD 64

// =====================================================================
// K1: k_pre — transpose + squared norms (sq chain matches k_cand dots).
// =====================================================================
__global__ __launch_bounds__(256) void k_pre(const float* __restrict__ x, float* __restrict__ xT,
                                             float* __restrict__ sq, int do_tr){
  __shared__ float tile[64*65];
  const int tid = threadIdx.x;
  const int b = blockIdx.x;
  for (int k = 0; k < 4; ++k){
    const int idx4 = tid + k*256;
    const float4 v = ((const float4*)(x + (size_t)b*4096))[idx4];
    const int row = idx4 >> 4, d0 = (idx4 & 15) * 4;
    tile[row*65 + d0 + 0] = v.x;
    tile[row*65 + d0 + 1] = v.y;
    tile[row*65 + d0 + 2] = v.z;
    tile[row*65 + d0 + 3] = v.w;
  }
  __syncthreads();
  if (do_tr){
    const int jj = tid & 15;
    const int dq = tid >> 4;
    for (int k = 0; k < 4; ++k){
      const int d = dq + 16*k;
      float4 o;
      o.x = tile[(jj*4+0)*65 + d];
      o.y = tile[(jj*4+1)*65 + d];
      o.z = tile[(jj*4+2)*65 + d];
      o.w = tile[(jj*4+3)*65 + d];
      ((float4*)xT)[(size_t)d*2048 + b*16 + jj] = o;
    }
  }
  if (tid < 64){
    float acc = 0.f;
    const float* rp = tile + tid*65;
    for (int d = 0; d < 64; ++d) acc = fmaf(rp[d], rp[d], acc);
    sq[b*64 + tid] = acc;
  }
}

// =====================================================================
// K2: k_cand — unchanged (bit-exact kNN/KDE path).
// =====================================================================
template<bool XT>
__device__ __forceinline__ void dists_1024(const float* __restrict__ x, const float* __restrict__ xT,
                                           const float* __restrict__ xi, int jbase, int tid,
                                           float acc[8][4]){
#pragma unroll
  for (int r = 0; r < 8; ++r)
#pragma unroll
    for (int q = 0; q < 4; ++q) acc[r][q] = 0.f;
  const int j0 = jbase + tid*4;
  for (int dq = 0; dq < 16; ++dq){
    float4 vj[4];
    if (XT){
#pragma unroll
      for (int s = 0; s < 4; ++s)
        vj[s] = ((const float4*)xT)[(size_t)(dq*4+s)*2048 + (j0 >> 2)];
    } else {
#pragma unroll
      for (int s = 0; s < 4; ++s){
        const int d = dq*4 + s;
        vj[s].x = x[(size_t)(j0+0)*64 + d];
        vj[s].y = x[(size_t)(j0+1)*64 + d];
        vj[s].z = x[(size_t)(j0+2)*64 + d];
        vj[s].w = x[(size_t)(j0+3)*64 + d];
      }
    }
#pragma unroll
    for (int r = 0; r < 8; ++r){
      const float4 wv = ((const float4*)(xi + r*64))[dq];
      acc[r][0] = fmaf(vj[0].x, wv.x, acc[r][0]);
      acc[r][1] = fmaf(vj[0].y, wv.x, acc[r][1]);
      acc[r][2] = fmaf(vj[0].z, wv.x, acc[r][2]);
      acc[r][3] = fmaf(vj[0].w, wv.x, acc[r][3]);
      acc[r][0] = fmaf(vj[1].x, wv.y, acc[r][0]);
      acc[r][1] = fmaf(vj[1].y, wv.y, acc[r][1]);
      acc[r][2] = fmaf(vj[1].z, wv.y, acc[r][2]);
      acc[r][3] = fmaf(vj[1].w, wv.y, acc[r][3]);
      acc[r][0] = fmaf(vj[2].x, wv.z, acc[r][0]);
      acc[r][1] = fmaf(vj[2].y, wv.z, acc[r][1]);
      acc[r][2] = fmaf(vj[2].z, wv.z, acc[r][2]);
      acc[r][3] = fmaf(vj[2].w, wv.z, acc[r][3]);
      acc[r][0] = fmaf(vj[3].x, wv.w, acc[r][0]);
      acc[r][1] = fmaf(vj[3].y, wv.w, acc[r][1]);
      acc[r][2] = fmaf(vj[3].z, wv.w, acc[r][2]);
      acc[r][3] = fmaf(vj[3].w, wv.w, acc[r][3]);
    }
  }
}

template<bool XT>
__global__ __launch_bounds__(256) void k_cand(const float* __restrict__ x, const float* __restrict__ xT,
                                              const float* __restrict__ sq,
                                              float* __restrict__ res, unsigned short* __restrict__ nn16){
  __shared__ float xi[8*64];
  __shared__ float sqi_s[8];
  __shared__ float tubs[8];
  __shared__ __align__(16) unsigned long long cand[8*512];
  __shared__ unsigned ccnt[8];
  float* samp = (float*)cand;
  const int tid = threadIdx.x;
  const int i0 = blockIdx.x * 8;
  for (int t = tid; t < 8*64; t += 256) xi[t] = x[(size_t)i0*64 + t];
  if (tid < 8){ sqi_s[tid] = sq[i0+tid]; ccnt[tid] = 0u; }
  __syncthreads();
  float sqir[8];
#pragma unroll
  for (int r = 0; r < 8; ++r) sqir[r] = sqi_s[r];

  const int w0 = (blockIdx.x * 1024) & 8191;
  {
    float acc[8][4];
    dists_1024<XT>(x, xT, xi, w0, tid, acc);
    float sqj[4];
#pragma unroll
    for (int q = 0; q < 4; ++q) sqj[q] = sq[w0 + tid*4 + q];
#pragma unroll
    for (int r = 0; r < 8; ++r)
#pragma unroll
      for (int q = 0; q < 4; ++q)
        samp[r*1024 + tid*4 + q] = (sqir[r] + sqj[q]) - 2.f*acc[r][q];
  }
  __syncthreads();
  {
    const int wv = tid >> 6, lane = tid & 63;
    for (int rr = 0; rr < 2; ++rr){
      const int r = wv + rr*4;
      float v[16];
#pragma unroll
      for (int k2 = 0; k2 < 16; ++k2) v[k2] = samp[r*1024 + lane + 64*k2];
      unsigned lo = 0u, hi = 0x7F800001u;
      while (hi - lo > 1u){
        const unsigned mid = (lo + hi) >> 1;
        const float pf = __uint_as_float(mid);
        int c = 0;
#pragma unroll
        for (int k2 = 0; k2 < 16; ++k2) c += (v[k2] < pf) ? 1 : 0;
#pragma unroll
        for (int off = 32; off; off >>= 1) c += __shfl_xor(c, off);
        if (c >= 32) hi = mid; else lo = mid;
      }
      if (lane == 0) tubs[r] = __uint_as_float(hi);
    }
  }
  __syncthreads();
  float tubr[8];
#pragma unroll
  for (int r = 0; r < 8; ++r) tubr[r] = tubs[r];
  for (int t = tid; t < 8*512; t += 256) cand[t] = ~0ULL;
  __syncthreads();

  for (int pass = 0; pass < 8; ++pass){
    const int jb = pass*1024;
    float acc[8][4];
    dists_1024<XT>(x, xT, xi, jb, tid, acc);
    const int j0 = jb + tid*4;
    float sqj[4];
#pragma unroll
    for (int q = 0; q < 4; ++q) sqj[q] = sq[j0 + q];
#pragma unroll
    for (int r = 0; r < 8; ++r){
#pragma unroll
      for (int q = 0; q < 4; ++q){
        const float dist = (sqir[r] + sqj[q]) - 2.f*acc[r][q];
        if (dist < tubr[r]){
          const unsigned pos = atomicAdd(&ccnt[r], 1u);
          if (pos < 512u){
            unsigned u = __float_as_uint(dist);
            u = ((int)u < 0) ? ~u : (u | 0x80000000u);
            cand[r*512 + pos] = (((unsigned long long)u) << 13) | (unsigned)(j0 + q);
          }
        }
      }
    }
  }
  __syncthreads();

  for (int k = 2; k <= 512; k <<= 1){
    for (int jj2 = k >> 1; jj2 > 0; jj2 >>= 1){
      const int mm = tid;
      const int i = ((mm & ~(jj2-1)) << 1) | (mm & (jj2-1));
      const int p = i | jj2;
      const bool up2 = ((i & k) == 0);
#pragma unroll
      for (int r = 0; r < 8; ++r){
        unsigned long long a = cand[r*512+i], bb = cand[r*512+p];
        if ((a > bb) == up2){ cand[r*512+i] = bb; cand[r*512+p] = a; }
      }
      __syncthreads();
    }
  }

  const int wv2 = tid >> 6, lane2 = tid & 63;
  for (int rr = 0; rr < 2; ++rr){
    const int r = wv2*2 + rr;
    const unsigned long long kk = cand[r*512 + lane2];
    float e = 0.f;
    if (lane2 < 50){
      unsigned u2 = (unsigned)(kk >> 13);
      u2 = (u2 & 0x80000000u) ? (u2 & 0x7FFFFFFFu) : ~u2;
      e = expf(-__uint_as_float(u2) / 30.f);
    }
#pragma unroll
    for (int off = 32; off; off >>= 1) e += __shfl_down(e, off);
    if (lane2 == 0) res[i0+r] = e / 1500.f;
    if (lane2 < 16) nn16[(size_t)(i0+r)*16 + lane2] = (unsigned short)(kk & 8191ULL);
  }
}

__device__ __forceinline__ unsigned long long shfl64_xor(unsigned long long v, int off){
  return (((unsigned long long)(unsigned)__shfl_xor((int)(v >> 32), off)) << 32)
       | (unsigned long long)(unsigned)__shfl_xor((int)(v & 0xFFFFFFFFu), off);
}

// =====================================================================
// K3: k_sort — max + stable bitonic argsort + ups lists (bit-exact).
// Writes dens_s (sorted densities) + ups_t (desc-sorted upward lists).
// =====================================================================
__global__ __launch_bounds__(1024) void k_sort(const float* __restrict__ res,
                                               const unsigned short* __restrict__ nn16,
                                               float* __restrict__ dens_s,
                                               unsigned short* __restrict__ ups_t){
  __shared__ __align__(16) unsigned long long keys[NN]; // 64KB
  __shared__ __align__(16) unsigned short rankv[NN];    // 16KB
  __shared__ float red[1024];
  const int tid = threadIdx.x;
  float m = 0.f;
  for (int t = tid; t < NN; t += 1024) m = fmaxf(m, res[t]);
  red[tid] = m; __syncthreads();
  for (int o = 512; o; o >>= 1){ if (tid < o) red[tid] = fmaxf(red[tid], red[tid+o]); __syncthreads(); }
  const float mr = red[0];
  for (int t = tid; t < NN; t += 1024){
    const float dnv = res[t] / mr;
    keys[t] = (((unsigned long long)__float_as_uint(dnv)) << 13) | (unsigned)t;
  }
  __syncthreads();
  for (int k = 2; k <= NN; k <<= 1){
    for (int j = k >> 1; j > 0; j >>= 1){
      for (int m2 = tid; m2 < NN/2; m2 += 1024){
        const int i = ((m2 & ~(j-1)) << 1) | (m2 & (j-1));
        const int p = i | j;
        const bool up = ((i & k) == 0);
        unsigned long long a = keys[i], b = keys[p];
        if ((a > b) == up){ keys[i] = b; keys[p] = a; }
      }
      __syncthreads();
    }
  }
  for (int t = tid; t < NN; t += 1024)
    rankv[(unsigned)(keys[t] & 8191ULL)] = (unsigned short)t;
  __syncthreads();
  for (int pp = 0; pp < 8; ++pp){
    const int p = tid + pp*1024;
    const unsigned long long kk = keys[p];
    dens_s[p] = __uint_as_float((unsigned)(kk >> 13));
    const unsigned orig = (unsigned)(kk & 8191ULL);
    const uint4 n0 = ((const uint4*)nn16)[(size_t)orig*2];
    const uint4 n1 = ((const uint4*)nn16)[(size_t)orig*2 + 1];
    unsigned nw[8] = {n0.x, n0.y, n0.z, n0.w, n1.x, n1.y, n1.z, n1.w};
    unsigned short outv[16];
    int cnt = 0;
    for (int k = 0; k < 16; ++k){
      const unsigned nb = (nw[k >> 1] >> ((k & 1) * 16)) & 0xFFFFu;
      const unsigned r = rankv[nb];
      if ((int)r > p){
        int q = cnt++;
        while (q > 0 && outv[q-1] < (unsigned short)r){ outv[q] = outv[q-1]; --q; }
        outv[q] = (unsigned short)r;
      }
    }
    for (int k = cnt; k < 16; ++k) outv[k] = 0;
    unsigned short* dst = ups_t + (size_t)p*16;
    uint4 a, b;
    a.x = (unsigned)outv[0] | ((unsigned)outv[1] << 16);
    a.y = (unsigned)outv[2] | ((unsigned)outv[3] << 16);
    a.z = (unsigned)outv[4] | ((unsigned)outv[5] << 16);
    a.w = (unsigned)outv[6] | ((unsigned)outv[7] << 16);
    b.x = (unsigned)outv[8] | ((unsigned)outv[9] << 16);
    b.y = (unsigned)outv[10] | ((unsigned)outv[11] << 16);
    b.z = (unsigned)outv[12] | ((unsigned)outv[13] << 16);
    b.w = (unsigned)outv[14] | ((unsigned)outv[15] << 16);
    ((uint4*)dst)[0] = a;
    ((uint4*)dst)[1] = b;
  }
}

// =====================================================================
// K4: k_msf — peak pointer-jumping + compacted Boruvka MSF + wave-batched
// Kruskal replay + loss. Same verified algorithm (rounds 6/7); B4 replay
// is now 64-edges-per-batch: parallel path-halving finds + register-only
// 64-step conflict resolution (readlane/cndmask) — removes the ~500cyc/edge
// single-thread dependent-LDS chain.
// =====================================================================
__device__ __forceinline__ unsigned uf_find2(volatile unsigned short* comp, unsigned x){
  unsigned r = comp[x];
  while (true){
    const unsigned g = comp[r];
    if (g == r) break;
    comp[x] = (unsigned short)g;   // halving (benign concurrent ancestor writes)
    x = r; r = g;
  }
  return r;
}

__global__ __launch_bounds__(1024) void k_msf(const float* __restrict__ dens_s,
                                              unsigned short* __restrict__ ups_t,
                                              unsigned long long* __restrict__ edges,
                                              int edgecap,
                                              float* __restrict__ out){
  __shared__ __align__(16) float dens[NN];              // 32KB
  __shared__ __align__(16) unsigned short P[NN];        // 16KB
  __shared__ __align__(16) unsigned short pkid[NN];     // 16KB
  __shared__ __align__(16) unsigned short death[NN];    // 16KB
  __shared__ __align__(16) unsigned short pkrank[4096]; // 8KB
  __shared__ __align__(16) unsigned short comp[4096];   // 8KB
  __shared__ __align__(16) unsigned short hook[4096];   // 8KB
  __shared__ __align__(16) unsigned bestv[4096];        // 16KB
  __shared__ __align__(16) unsigned long long msf[4096];// 32KB
  __shared__ unsigned long long wred[17];
  __shared__ unsigned long long sel[10];
  __shared__ unsigned ecnt_s, ecnt2_s, mcnt_s, chg_s, flat_s, dcnt_s;
  unsigned* scan1 = (unsigned*)msf;   // A5b only (msf dead then)
  float* red = (float*)msf;           // loss S-sum only (msf dead then)
  unsigned* dlist = bestv;            // loss only (bestv dead then)

  const int tid = threadIdx.x;
  const int lane = tid & 63;

  // ---- load + init ----
  for (int t = tid; t < NN/4; t += 1024)
    ((float4*)dens)[t] = ((const float4*)dens_s)[t];
  for (int t = tid; t < NN; t += 1024){
    const unsigned u0 = ups_t[(size_t)t*16];
    P[t] = (u0 == 0u) ? (unsigned short)t : (unsigned short)u0;
    death[t] = 0xFFFFu;
  }
  if (tid == 0){ ecnt_s = 0u; mcnt_s = 0u; dcnt_s = 0u; }
  __syncthreads();

  // ---- A5: pointer jumping -> P = u_max forest root (races benign) ----
  for (int rd = 0; rd < 13; ++rd){
    for (int pp = 0; pp < 8; ++pp){
      const int p = tid + pp*1024;
      const unsigned v = P[p];
      const unsigned w2 = P[v];
      if (w2 != v) P[p] = (unsigned short)w2;
    }
    __syncthreads();
  }

  // ---- A5b: peak compaction ----
  {
    const int p0 = tid*8;
    int c = 0;
    for (int k = 0; k < 8; ++k) c += (P[p0+k] == (unsigned short)(p0+k)) ? 1 : 0;
    scan1[tid] = (unsigned)c; __syncthreads();
    for (int s = 1; s < 1024; s <<= 1){
      const unsigned v = scan1[tid];
      const unsigned u = (tid >= s) ? scan1[tid-s] : 0u;
      __syncthreads();
      scan1[tid] = v + u;
      __syncthreads();
    }
    int base = (int)scan1[tid] - c;
    for (int k = 0; k < 8; ++k){
      const int p = p0 + k;
      if (P[p] == (unsigned short)p){
        pkid[p] = (unsigned short)base;
        if (base < 4096) pkrank[base] = (unsigned short)p;
        ++base;
      }
    }
  }
  __syncthreads();
  int Npk = (int)scan1[1023];
  if (Npk > 4096) Npk = 4096;
  __syncthreads();

  // ---- B1: compact-id edge list (wave-aggregated append) ----
  for (int pp = 0; pp < 8; ++pp){
    const int p = tid + pp*1024;
    const uint4 a4 = ((const uint4*)ups_t)[(size_t)p*2];
    const uint4 b4 = ((const uint4*)ups_t)[(size_t)p*2 + 1];
    unsigned uu[8] = {a4.x, a4.y, a4.z, a4.w, b4.x, b4.y, b4.z, b4.w};
    unsigned edv[15];
    int nd = 0;
    const unsigned u0 = uu[0] & 0xFFFFu;
    if (u0 != 0u){
      const unsigned m0 = P[u0];
      const unsigned m0id = pkid[m0];
      for (int k = 1; k < 16; ++k){
        const unsigned uk = (uu[k >> 1] >> ((k & 1) * 16)) & 0xFFFFu;
        if (uk == 0u) break;
        const unsigned v = P[uk];
        if (v == m0) continue;
        const unsigned vid = pkid[v];
        bool dup = false;
        for (int j = 0; j < nd; ++j) dup = dup || ((edv[j] >> 16) == vid);
        if (dup) continue;
        edv[nd++] = (vid << 16) | m0id;
      }
    }
    unsigned off = (unsigned)nd;
    for (int s = 1; s < 64; s <<= 1){
      const unsigned o = (unsigned)__shfl_up((int)off, s);
      if (lane >= s) off += o;
    }
    const unsigned tot = (unsigned)__shfl((int)off, 63);
    unsigned wb = 0u;
    if (lane == 0 && tot) wb = atomicAdd(&ecnt_s, tot);
    wb = (unsigned)__shfl((int)wb, 0);
    const unsigned mybase = wb + off - (unsigned)nd;
    for (int k = 0; k < nd; ++k){
      const unsigned pos = mybase + (unsigned)k;
      if ((int)pos < edgecap)
        edges[pos] = (((unsigned long long)(unsigned)p) << 32) | (unsigned long long)edv[k];
    }
  }
  __syncthreads();
  int Ecur = ((int)ecnt_s < edgecap) ? (int)ecnt_s : edgecap;

  // ---- B2: Boruvka MSF over compact peak graph ----
  unsigned long long* eb_in  = edges;
  unsigned long long* eb_out = (unsigned long long*)ups_t;   // dead after B1
  for (int t = tid; t < Npk; t += 1024) comp[t] = (unsigned short)t;
  __syncthreads();
  for (int round = 0; round < 16 && Ecur > 0; ++round){
    for (int t = tid; t < Npk; t += 1024){ bestv[t] = 0u; hook[t] = 0xFFFFu; }
    if (tid == 0){ chg_s = 0u; ecnt2_s = 0u; }
    __syncthreads();
    for (int base = 0; base < Ecur; base += 1024){
      const int e = base + tid;
      bool keep = false;
      unsigned long long ed = 0ULL;
      if (e < Ecur){
        ed = eb_in[e];
        const unsigned a = (unsigned)(ed >> 16) & 0xFFFFu;
        const unsigned b = (unsigned)ed & 0xFFFFu;
        const unsigned ra = comp[a], rb = comp[b];
        if (ra != rb){
          keep = true;
          const unsigned key = ((((unsigned)(ed >> 32)) + 1u) << 18) | (unsigned)e;
          atomicMax(&bestv[ra], key);
          atomicMax(&bestv[rb], key);
        }
      }
      const unsigned long long bal = __ballot(keep);
      const unsigned cnt = (unsigned)__popcll(bal);
      const unsigned pfx = (unsigned)__popcll(bal & ((1ULL << lane) - 1ULL));
      unsigned wb = 0u;
      if (lane == 0 && cnt) wb = atomicAdd(&ecnt2_s, cnt);
      wb = (unsigned)__shfl((int)wb, 0);
      if (keep && (wb + pfx) < 32768u) eb_out[wb + pfx] = ed;
    }
    __syncthreads();
    for (int t = tid; t < Npk; t += 1024){
      if (comp[t] == (unsigned short)t && bestv[t] != 0u){
        const unsigned long long ed = eb_in[bestv[t] & 0x3FFFFu];
        const unsigned a = (unsigned)(ed >> 16) & 0xFFFFu;
        const unsigned b = (unsigned)ed & 0xFFFFu;
        const unsigned ra = comp[a], rb = comp[b];
        hook[t] = (unsigned short)((ra == (unsigned)t) ? rb : ra);
      }
    }
    __syncthreads();
    for (int t = tid; t < Npk; t += 1024){
      const unsigned o = hook[t];
      if (o != 0xFFFFu && !(hook[o] == (unsigned short)t && (unsigned)t < o)){
        comp[t] = (unsigned short)o;
        chg_s = 1u;
        const unsigned long long ed = eb_in[bestv[t] & 0x3FFFFu];
        const unsigned pos = atomicAdd(&mcnt_s, 1u);
        if (pos < 4096u) msf[pos] = (((ed >> 32) + 1ULL) << 32) | (ed & 0xFFFFFFFFULL);
      }
    }
    __syncthreads();
    for (;;){
      if (tid == 0) flat_s = 0u;
      __syncthreads();
      for (int t = tid; t < Npk; t += 1024){
        const unsigned c = comp[t];
        const unsigned cc = comp[c];
        if (cc != c){ comp[t] = (unsigned short)cc; flat_s = 1u; }
      }
      __syncthreads();
      if (flat_s == 0u) break;
    }
    const int En = ((int)ecnt2_s < 32768) ? (int)ecnt2_s : 32767;
    const unsigned ch = chg_s;
    __syncthreads();
    Ecur = En;
    { unsigned long long* t2 = eb_in; eb_in = eb_out; eb_out = t2; }
    if (ch == 0u) break;
  }

  // ---- B3: sort MSF edges descending ----
  const int M = ((int)mcnt_s < 4096) ? (int)mcnt_s : 4095;
  int W = 64; while (W < M) W <<= 1;
  for (int t = M + tid; t < W; t += 1024) msf[t] = 0ULL;
  for (int t = tid; t < Npk; t += 1024) comp[t] = (unsigned short)t;  // reset for replay
  __syncthreads();
  for (int k = 2; k <= W; k <<= 1){
    for (int j = k >> 1; j > 0; j >>= 1){
      for (int m2 = tid; m2 < W/2; m2 += 1024){
        const int i = ((m2 & ~(j-1)) << 1) | (m2 & (j-1));
        const int p = i | j;
        const bool up = ((i & k) == 0);
        const unsigned long long a = msf[i], b = msf[p];
        if ((a < b) == up){ msf[i] = b; msf[p] = a; }   // descending
      }
      __syncthreads();
    }
  }

  // ---- B4: wave-batched Kruskal replay ----
  {
    const int nb = (M + 63) >> 6;
    for (int bch = 0; bch < nb; ++bch){
      if (tid < 64){
        const int ei = bch*64 + lane;
        unsigned ra = 0xFFFFu, rb = 0xFFFFu, wgt = 0u;
        if (ei < M){
          const unsigned long long e = msf[ei];
          const unsigned a = ((unsigned)e >> 16) & 0xFFFFu;
          const unsigned b = (unsigned)e & 0xFFFFu;
          wgt = (unsigned)(e >> 32) - 1u;
          ra = uf_find2(comp, a);
          rb = uf_find2(comp, b);
        }
        unsigned kra = 0xFFFFu, krb = 0xFFFFu;
        for (int i = 0; i < 64; ++i){
          const unsigned rai = (unsigned)__builtin_amdgcn_readlane((int)ra, i);
          const unsigned rbi = (unsigned)__builtin_amdgcn_readlane((int)rb, i);
          if (rai == 0xFFFFu || rai == rbi) continue;   // invalid or self-loop
          if (lane == i){ kra = rai; krb = rbi; }
          ra = (ra == rai) ? rbi : ra;
          rb = (rb == rai) ? rbi : rb;
        }
        if (kra != 0xFFFFu){
          death[pkrank[kra]] = (unsigned short)wgt;   // distinct kra -> no conflicts
          comp[kra] = (unsigned short)krb;
        }
      }
      __syncthreads();
      for (int t = tid; t < Npk; t += 1024){
        const unsigned c = comp[t];
        const unsigned cc = comp[c];
        if (cc != c) comp[t] = (unsigned short)cc;
      }
      __syncthreads();
    }
  }
  __syncthreads();

  // ---- loss: S (bit-exact strided order) ----
  float s = 0.f;
  for (int e = tid; e < NN; e += 1024){
    const int dr = death[e];
    if (dr != 0xFFFF) s += dens[e] - dens[dr];
  }
  red[tid] = s; __syncthreads();
  for (int o = 512; o; o >>= 1){ if (tid < o) red[tid] += red[tid+o]; __syncthreads(); }
  const float S = red[0];

  // ---- loss: compact death list ----
  for (int e8 = 0; e8 < 8; ++e8){
    const int e = tid + e8*1024;
    const int dr = death[e];
    const bool have = (dr != 0xFFFF);
    const unsigned long long bal = __ballot(have);
    const unsigned cnt = (unsigned)__popcll(bal);
    const unsigned pfx = (unsigned)__popcll(bal & ((1ULL << lane) - 1ULL));
    unsigned wb = 0u;
    if (lane == 0 && cnt) wb = atomicAdd(&dcnt_s, cnt);
    wb = (unsigned)__shfl((int)wb, 0);
    if (have && (wb + pfx) < 4096u) dlist[wb + pfx] = ((unsigned)e << 13) | (unsigned)dr;
  }
  __syncthreads();
  const int Dm = ((int)dcnt_s < 4096) ? (int)dcnt_s : 4096;

  // ---- loss: top-10 (max over distinct keys: order-free, exact) ----
  unsigned long long last = ~0ULL;
  for (int t10 = 0; t10 < 10; ++t10){
    unsigned long long km = 0ULL;
    for (int i = tid; i < Dm; i += 1024){
      const unsigned pk = dlist[i];
      const unsigned e = pk >> 13, dr = pk & 8191u;
      const float pers = dens[e] - dens[dr];
      const unsigned long long k = (((unsigned long long)__float_as_uint(pers)) << 13) | e;
      if (k < last && k > km) km = k;
    }
    for (int off = 32; off; off >>= 1){
      const unsigned long long o = shfl64_xor(km, off);
      km = (o > km) ? o : km;
    }
    if (lane == 0) wred[tid >> 6] = km;
    __syncthreads();
    if (tid < 64){
      unsigned long long v = (tid < 16) ? wred[tid] : 0ULL;
      for (int off = 8; off; off >>= 1){
        const unsigned long long o = shfl64_xor(v, off);
        v = (o > v) ? o : v;
      }
      if (tid == 0) wred[16] = v;
    }
    __syncthreads();
    const unsigned long long st = wred[16];
    if (tid == 0) sel[t10] = st;
    last = st;
    __syncthreads();
  }
  if (tid == 0){
    float top = 0.f;
    for (int t10 = 0; t10 < 10; ++t10)
      if (sel[t10]) top += __uint_as_float((unsigned)(sel[t10] >> 13));
    float strong = 0.f, dest0 = 0.f, dest1 = 0.f;
    if (sel[0]){
      const unsigned e0 = (unsigned)(sel[0] & 8191ULL);
      dest0 = dens[e0]; dest1 = dens[death[e0]];
    }
    for (int t10 = 1; t10 < 10; ++t10){
      if (!sel[t10]) continue;
      const unsigned e = (unsigned)(sel[t10] & 8191ULL);
      const float a = dens[e] - dest0;
      const float b = dens[death[e]] - dest1;
      strong += sqrtf(a*a + b*b);
    }
    out[0] = (S - top) / 1.41421356237309515f + strong;
  }
}

// =====================================================================
// launch — 4 dispatches (k_suf split for phase attribution)
// =====================================================================
extern "C" void kernel_launch(void* const* d_in, const int* in_sizes, int n_in,
                              void* d_out, int out_size, void* d_ws, size_t ws_size,
                              hipStream_t stream){
  const float* x = (const float*)d_in[0];
  char* w = (char*)d_ws;
  float*          sq     = (float*)(w + 0);                 // 32KB
  float*          res    = (float*)(w + 32768);             // 32KB
  float*          dens_s = (float*)(w + 65536);             // 32KB
  unsigned short* nn16   = (unsigned short*)(w + 98304);    // 256KB
  unsigned short* ups_t  = (unsigned short*)(w + 360448);   // 256KB (edge ping-pong in B2)
  float*          xT     = (float*)(w + 622592);            // 2MB (optional)
  const int use_xt = (ws_size >= (size_t)(622592 + NN*DD*4)) ? 1 : 0;
  unsigned long long* edges = use_xt ? (unsigned long long*)(w + 622592)
                                     : (unsigned long long*)(w + 98304);
  const int edgecap = use_xt ? 262143 : 32767;

  k_pre<<<128, 256, 0, stream>>>(x, xT, sq, use_xt);
  if (use_xt) k_cand<true ><<<1024, 256, 0, stream>>>(x, xT, sq, res, nn16);
  else        k_cand<false><<<1024, 256, 0, stream>>>(x, xT, sq, res, nn16);
  k_sort<<<1, 1024, 0, stream>>>(res, nn16, dens_s, ups_t);
  k_msf<<<1, 1024, 0, stream>>>(dens_s, ups_t, edges, edgecap, (float*)d_out);
}

// Round 9
// 526.759 us; speedup vs baseline: 2.0303x; 1.9600x over previous
//
#include <hip/hip_runtime.h>
#include <stdint.h>

#define NN 8192
#define DD 64

// =====================================================================
// K1: k_pre — transpose + squared norms (sq chain matches k_cand dots).
// =====================================================================
__global__ __launch_bounds__(256) void k_pre(const float* __restrict__ x, float* __restrict__ xT,
                                             float* __restrict__ sq, int do_tr){
  __shared__ float tile[64*65];
  const int tid = threadIdx.x;
  const int b = blockIdx.x;
  for (int k = 0; k < 4; ++k){
    const int idx4 = tid + k*256;
    const float4 v = ((const float4*)(x + (size_t)b*4096))[idx4];
    const int row = idx4 >> 4, d0 = (idx4 & 15) * 4;
    tile[row*65 + d0 + 0] = v.x;
    tile[row*65 + d0 + 1] = v.y;
    tile[row*65 + d0 + 2] = v.z;
    tile[row*65 + d0 + 3] = v.w;
  }
  __syncthreads();
  if (do_tr){
    const int jj = tid & 15;
    const int dq = tid >> 4;
    for (int k = 0; k < 4; ++k){
      const int d = dq + 16*k;
      float4 o;
      o.x = tile[(jj*4+0)*65 + d];
      o.y = tile[(jj*4+1)*65 + d];
      o.z = tile[(jj*4+2)*65 + d];
      o.w = tile[(jj*4+3)*65 + d];
      ((float4*)xT)[(size_t)d*2048 + b*16 + jj] = o;
    }
  }
  if (tid < 64){
    float acc = 0.f;
    const float* rp = tile + tid*65;
    for (int d = 0; d < 64; ++d) acc = fmaf(rp[d], rp[d], acc);
    sq[b*64 + tid] = acc;
  }
}

// =====================================================================
// K2: k_cand — unchanged (bit-exact kNN/KDE path).
// =====================================================================
template<bool XT>
__device__ __forceinline__ void dists_1024(const float* __restrict__ x, const float* __restrict__ xT,
                                           const float* __restrict__ xi, int jbase, int tid,
                                           float acc[8][4]){
#pragma unroll
  for (int r = 0; r < 8; ++r)
#pragma unroll
    for (int q = 0; q < 4; ++q) acc[r][q] = 0.f;
  const int j0 = jbase + tid*4;
  for (int dq = 0; dq < 16; ++dq){
    float4 vj[4];
    if (XT){
#pragma unroll
      for (int s = 0; s < 4; ++s)
        vj[s] = ((const float4*)xT)[(size_t)(dq*4+s)*2048 + (j0 >> 2)];
    } else {
#pragma unroll
      for (int s = 0; s < 4; ++s){
        const int d = dq*4 + s;
        vj[s].x = x[(size_t)(j0+0)*64 + d];
        vj[s].y = x[(size_t)(j0+1)*64 + d];
        vj[s].z = x[(size_t)(j0+2)*64 + d];
        vj[s].w = x[(size_t)(j0+3)*64 + d];
      }
    }
#pragma unroll
    for (int r = 0; r < 8; ++r){
      const float4 wv = ((const float4*)(xi + r*64))[dq];
      acc[r][0] = fmaf(vj[0].x, wv.x, acc[r][0]);
      acc[r][1] = fmaf(vj[0].y, wv.x, acc[r][1]);
      acc[r][2] = fmaf(vj[0].z, wv.x, acc[r][2]);
      acc[r][3] = fmaf(vj[0].w, wv.x, acc[r][3]);
      acc[r][0] = fmaf(vj[1].x, wv.y, acc[r][0]);
      acc[r][1] = fmaf(vj[1].y, wv.y, acc[r][1]);
      acc[r][2] = fmaf(vj[1].z, wv.y, acc[r][2]);
      acc[r][3] = fmaf(vj[1].w, wv.y, acc[r][3]);
      acc[r][0] = fmaf(vj[2].x, wv.z, acc[r][0]);
      acc[r][1] = fmaf(vj[2].y, wv.z, acc[r][1]);
      acc[r][2] = fmaf(vj[2].z, wv.z, acc[r][2]);
      acc[r][3] = fmaf(vj[2].w, wv.z, acc[r][3]);
      acc[r][0] = fmaf(vj[3].x, wv.w, acc[r][0]);
      acc[r][1] = fmaf(vj[3].y, wv.w, acc[r][1]);
      acc[r][2] = fmaf(vj[3].z, wv.w, acc[r][2]);
      acc[r][3] = fmaf(vj[3].w, wv.w, acc[r][3]);
    }
  }
}

template<bool XT>
__global__ __launch_bounds__(256) void k_cand(const float* __restrict__ x, const float* __restrict__ xT,
                                              const float* __restrict__ sq,
                                              float* __restrict__ res, unsigned short* __restrict__ nn16){
  __shared__ float xi[8*64];
  __shared__ float sqi_s[8];
  __shared__ float tubs[8];
  __shared__ __align__(16) unsigned long long cand[8*512];
  __shared__ unsigned ccnt[8];
  float* samp = (float*)cand;
  const int tid = threadIdx.x;
  const int i0 = blockIdx.x * 8;
  for (int t = tid; t < 8*64; t += 256) xi[t] = x[(size_t)i0*64 + t];
  if (tid < 8){ sqi_s[tid] = sq[i0+tid]; ccnt[tid] = 0u; }
  __syncthreads();
  float sqir[8];
#pragma unroll
  for (int r = 0; r < 8; ++r) sqir[r] = sqi_s[r];

  const int w0 = (blockIdx.x * 1024) & 8191;
  {
    float acc[8][4];
    dists_1024<XT>(x, xT, xi, w0, tid, acc);
    float sqj[4];
#pragma unroll
    for (int q = 0; q < 4; ++q) sqj[q] = sq[w0 + tid*4 + q];
#pragma unroll
    for (int r = 0; r < 8; ++r)
#pragma unroll
      for (int q = 0; q < 4; ++q)
        samp[r*1024 + tid*4 + q] = (sqir[r] + sqj[q]) - 2.f*acc[r][q];
  }
  __syncthreads();
  {
    const int wv = tid >> 6, lane = tid & 63;
    for (int rr = 0; rr < 2; ++rr){
      const int r = wv + rr*4;
      float v[16];
#pragma unroll
      for (int k2 = 0; k2 < 16; ++k2) v[k2] = samp[r*1024 + lane + 64*k2];
      unsigned lo = 0u, hi = 0x7F800001u;
      while (hi - lo > 1u){
        const unsigned mid = (lo + hi) >> 1;
        const float pf = __uint_as_float(mid);
        int c = 0;
#pragma unroll
        for (int k2 = 0; k2 < 16; ++k2) c += (v[k2] < pf) ? 1 : 0;
#pragma unroll
        for (int off = 32; off; off >>= 1) c += __shfl_xor(c, off);
        if (c >= 32) hi = mid; else lo = mid;
      }
      if (lane == 0) tubs[r] = __uint_as_float(hi);
    }
  }
  __syncthreads();
  float tubr[8];
#pragma unroll
  for (int r = 0; r < 8; ++r) tubr[r] = tubs[r];
  for (int t = tid; t < 8*512; t += 256) cand[t] = ~0ULL;
  __syncthreads();

  for (int pass = 0; pass < 8; ++pass){
    const int jb = pass*1024;
    float acc[8][4];
    dists_1024<XT>(x, xT, xi, jb, tid, acc);
    const int j0 = jb + tid*4;
    float sqj[4];
#pragma unroll
    for (int q = 0; q < 4; ++q) sqj[q] = sq[j0 + q];
#pragma unroll
    for (int r = 0; r < 8; ++r){
#pragma unroll
      for (int q = 0; q < 4; ++q){
        const float dist = (sqir[r] + sqj[q]) - 2.f*acc[r][q];
        if (dist < tubr[r]){
          const unsigned pos = atomicAdd(&ccnt[r], 1u);
          if (pos < 512u){
            unsigned u = __float_as_uint(dist);
            u = ((int)u < 0) ? ~u : (u | 0x80000000u);
            cand[r*512 + pos] = (((unsigned long long)u) << 13) | (unsigned)(j0 + q);
          }
        }
      }
    }
  }
  __syncthreads();

  for (int k = 2; k <= 512; k <<= 1){
    for (int jj2 = k >> 1; jj2 > 0; jj2 >>= 1){
      const int mm = tid;
      const int i = ((mm & ~(jj2-1)) << 1) | (mm & (jj2-1));
      const int p = i | jj2;
      const bool up2 = ((i & k) == 0);
#pragma unroll
      for (int r = 0; r < 8; ++r){
        unsigned long long a = cand[r*512+i], bb = cand[r*512+p];
        if ((a > bb) == up2){ cand[r*512+i] = bb; cand[r*512+p] = a; }
      }
      __syncthreads();
    }
  }

  const int wv2 = tid >> 6, lane2 = tid & 63;
  for (int rr = 0; rr < 2; ++rr){
    const int r = wv2*2 + rr;
    const unsigned long long kk = cand[r*512 + lane2];
    float e = 0.f;
    if (lane2 < 50){
      unsigned u2 = (unsigned)(kk >> 13);
      u2 = (u2 & 0x80000000u) ? (u2 & 0x7FFFFFFFu) : ~u2;
      e = expf(-__uint_as_float(u2) / 30.f);
    }
#pragma unroll
    for (int off = 32; off; off >>= 1) e += __shfl_down(e, off);
    if (lane2 == 0) res[i0+r] = e / 1500.f;
    if (lane2 < 16) nn16[(size_t)(i0+r)*16 + lane2] = (unsigned short)(kk & 8191ULL);
  }
}

__device__ __forceinline__ unsigned long long shfl64_xor(unsigned long long v, int off){
  return (((unsigned long long)(unsigned)__shfl_xor((int)(v >> 32), off)) << 32)
       | (unsigned long long)(unsigned)__shfl_xor((int)(v & 0xFFFFFFFFu), off);
}

// =====================================================================
// K3: k_rank — direct rank computation (replaces the single-CU bitonic).
// rank[i] = #{j : key[j] < key[i]}, key = dnv_bits<<13 | i (all distinct)
// == exact stable-argsort position, bit-identical to jnp.argsort.
// 64 blocks; keys staged in LDS; wave-uniform broadcast reads.
// =====================================================================
__global__ __launch_bounds__(256) void k_rank(const float* __restrict__ res,
                                              unsigned short* __restrict__ rank,
                                              float* __restrict__ dens_s){
  __shared__ __align__(16) unsigned long long keys[NN]; // 64KB
  __shared__ float red[256];
  __shared__ unsigned short pcnt[256];
  const int tid = threadIdx.x;
  float m = 0.f;
  for (int t = tid; t < NN; t += 256) m = fmaxf(m, res[t]);
  red[tid] = m; __syncthreads();
  for (int o = 128; o; o >>= 1){ if (tid < o) red[tid] = fmaxf(red[tid], red[tid+o]); __syncthreads(); }
  const float mr = red[0];
  __syncthreads();
  for (int t = tid; t < NN; t += 256){
    const float dnv = res[t] / mr;
    keys[t] = (((unsigned long long)__float_as_uint(dnv)) << 13) | (unsigned)t;
  }
  __syncthreads();
  const int i = blockIdx.x*128 + (tid & 127);
  const unsigned long long ki = keys[i];
  const int j0 = (tid >> 7) * (NN/2);      // wave-uniform half-split
  int c = 0;
#pragma unroll 8
  for (int j = 0; j < NN/2; ++j) c += (keys[j0 + j] < ki) ? 1 : 0;
  pcnt[tid] = (unsigned short)c;
  __syncthreads();
  if (tid < 128){
    const int r = (int)pcnt[tid] + (int)pcnt[tid + 128];
    rank[i] = (unsigned short)r;
    dens_s[r] = __uint_as_float((unsigned)(ki >> 13));   // bit-identical scatter
  }
}

// =====================================================================
// K4: k_ups — upward-neighbour lists (desc-sorted, 0-padded) via rank[].
// 32 blocks; rank[] staged in LDS.
// =====================================================================
__global__ __launch_bounds__(256) void k_ups(const unsigned short* __restrict__ rank,
                                             const unsigned short* __restrict__ nn16,
                                             unsigned short* __restrict__ ups_t){
  __shared__ __align__(16) unsigned short rk[NN]; // 16KB
  const int tid = threadIdx.x;
  for (int t = tid; t < NN/8; t += 256) ((uint4*)rk)[t] = ((const uint4*)rank)[t];
  __syncthreads();
  const int o = blockIdx.x*256 + tid;
  const int p = rk[o];
  const uint4 n0 = ((const uint4*)nn16)[(size_t)o*2];
  const uint4 n1 = ((const uint4*)nn16)[(size_t)o*2 + 1];
  unsigned nw[8] = {n0.x, n0.y, n0.z, n0.w, n1.x, n1.y, n1.z, n1.w};
  unsigned short outv[16];
  int cnt = 0;
  for (int k = 0; k < 16; ++k){
    const unsigned nb = (nw[k >> 1] >> ((k & 1) * 16)) & 0xFFFFu;
    const unsigned r = rk[nb];
    if ((int)r > p){
      int q = cnt++;
      while (q > 0 && outv[q-1] < (unsigned short)r){ outv[q] = outv[q-1]; --q; }
      outv[q] = (unsigned short)r;
    }
  }
  for (int k = cnt; k < 16; ++k) outv[k] = 0;
  unsigned short* dst = ups_t + (size_t)p*16;
  uint4 a, b;
  a.x = (unsigned)outv[0] | ((unsigned)outv[1] << 16);
  a.y = (unsigned)outv[2] | ((unsigned)outv[3] << 16);
  a.z = (unsigned)outv[4] | ((unsigned)outv[5] << 16);
  a.w = (unsigned)outv[6] | ((unsigned)outv[7] << 16);
  b.x = (unsigned)outv[8] | ((unsigned)outv[9] << 16);
  b.y = (unsigned)outv[10] | ((unsigned)outv[11] << 16);
  b.z = (unsigned)outv[12] | ((unsigned)outv[13] << 16);
  b.w = (unsigned)outv[14] | ((unsigned)outv[15] << 16);
  ((uint4*)dst)[0] = a;
  ((uint4*)dst)[1] = b;
}

// =====================================================================
// K5: k_msf — unchanged from round 8 (verified Boruvka-MSF + batched replay).
// =====================================================================
__device__ __forceinline__ unsigned uf_find2(volatile unsigned short* comp, unsigned x){
  unsigned r = comp[x];
  while (true){
    const unsigned g = comp[r];
    if (g == r) break;
    comp[x] = (unsigned short)g;
    x = r; r = g;
  }
  return r;
}

__global__ __launch_bounds__(1024) void k_msf(const float* __restrict__ dens_s,
                                              unsigned short* __restrict__ ups_t,
                                              unsigned long long* __restrict__ edges,
                                              int edgecap,
                                              float* __restrict__ out){
  __shared__ __align__(16) float dens[NN];              // 32KB
  __shared__ __align__(16) unsigned short P[NN];        // 16KB
  __shared__ __align__(16) unsigned short pkid[NN];     // 16KB
  __shared__ __align__(16) unsigned short death[NN];    // 16KB
  __shared__ __align__(16) unsigned short pkrank[4096]; // 8KB
  __shared__ __align__(16) unsigned short comp[4096];   // 8KB
  __shared__ __align__(16) unsigned short hook[4096];   // 8KB
  __shared__ __align__(16) unsigned bestv[4096];        // 16KB
  __shared__ __align__(16) unsigned long long msf[4096];// 32KB
  __shared__ unsigned long long wred[17];
  __shared__ unsigned long long sel[10];
  __shared__ unsigned ecnt_s, ecnt2_s, mcnt_s, chg_s, flat_s, dcnt_s;
  unsigned* scan1 = (unsigned*)msf;
  float* red = (float*)msf;
  unsigned* dlist = bestv;

  const int tid = threadIdx.x;
  const int lane = tid & 63;

  for (int t = tid; t < NN/4; t += 1024)
    ((float4*)dens)[t] = ((const float4*)dens_s)[t];
  for (int t = tid; t < NN; t += 1024){
    const unsigned u0 = ups_t[(size_t)t*16];
    P[t] = (u0 == 0u) ? (unsigned short)t : (unsigned short)u0;
    death[t] = 0xFFFFu;
  }
  if (tid == 0){ ecnt_s = 0u; mcnt_s = 0u; dcnt_s = 0u; }
  __syncthreads();

  for (int rd = 0; rd < 13; ++rd){
    for (int pp = 0; pp < 8; ++pp){
      const int p = tid + pp*1024;
      const unsigned v = P[p];
      const unsigned w2 = P[v];
      if (w2 != v) P[p] = (unsigned short)w2;
    }
    __syncthreads();
  }

  {
    const int p0 = tid*8;
    int c = 0;
    for (int k = 0; k < 8; ++k) c += (P[p0+k] == (unsigned short)(p0+k)) ? 1 : 0;
    scan1[tid] = (unsigned)c; __syncthreads();
    for (int s = 1; s < 1024; s <<= 1){
      const unsigned v = scan1[tid];
      const unsigned u = (tid >= s) ? scan1[tid-s] : 0u;
      __syncthreads();
      scan1[tid] = v + u;
      __syncthreads();
    }
    int base = (int)scan1[tid] - c;
    for (int k = 0; k < 8; ++k){
      const int p = p0 + k;
      if (P[p] == (unsigned short)p){
        pkid[p] = (unsigned short)base;
        if (base < 4096) pkrank[base] = (unsigned short)p;
        ++base;
      }
    }
  }
  __syncthreads();
  int Npk = (int)scan1[1023];
  if (Npk > 4096) Npk = 4096;
  __syncthreads();

  for (int pp = 0; pp < 8; ++pp){
    const int p = tid + pp*1024;
    const uint4 a4 = ((const uint4*)ups_t)[(size_t)p*2];
    const uint4 b4 = ((const uint4*)ups_t)[(size_t)p*2 + 1];
    unsigned uu[8] = {a4.x, a4.y, a4.z, a4.w, b4.x, b4.y, b4.z, b4.w};
    unsigned edv[15];
    int nd = 0;
    const unsigned u0 = uu[0] & 0xFFFFu;
    if (u0 != 0u){
      const unsigned m0 = P[u0];
      const unsigned m0id = pkid[m0];
      for (int k = 1; k < 16; ++k){
        const unsigned uk = (uu[k >> 1] >> ((k & 1) * 16)) & 0xFFFFu;
        if (uk == 0u) break;
        const unsigned v = P[uk];
        if (v == m0) continue;
        const unsigned vid = pkid[v];
        bool dup = false;
        for (int j = 0; j < nd; ++j) dup = dup || ((edv[j] >> 16) == vid);
        if (dup) continue;
        edv[nd++] = (vid << 16) | m0id;
      }
    }
    unsigned off = (unsigned)nd;
    for (int s = 1; s < 64; s <<= 1){
      const unsigned o = (unsigned)__shfl_up((int)off, s);
      if (lane >= s) off += o;
    }
    const unsigned tot = (unsigned)__shfl((int)off, 63);
    unsigned wb = 0u;
    if (lane == 0 && tot) wb = atomicAdd(&ecnt_s, tot);
    wb = (unsigned)__shfl((int)wb, 0);
    const unsigned mybase = wb + off - (unsigned)nd;
    for (int k = 0; k < nd; ++k){
      const unsigned pos = mybase + (unsigned)k;
      if ((int)pos < edgecap)
        edges[pos] = (((unsigned long long)(unsigned)p) << 32) | (unsigned long long)edv[k];
    }
  }
  __syncthreads();
  int Ecur = ((int)ecnt_s < edgecap) ? (int)ecnt_s : edgecap;

  unsigned long long* eb_in  = edges;
  unsigned long long* eb_out = (unsigned long long*)ups_t;
  for (int t = tid; t < Npk; t += 1024) comp[t] = (unsigned short)t;
  __syncthreads();
  for (int round = 0; round < 16 && Ecur > 0; ++round){
    for (int t = tid; t < Npk; t += 1024){ bestv[t] = 0u; hook[t] = 0xFFFFu; }
    if (tid == 0){ chg_s = 0u; ecnt2_s = 0u; }
    __syncthreads();
    for (int base = 0; base < Ecur; base += 1024){
      const int e = base + tid;
      bool keep = false;
      unsigned long long ed = 0ULL;
      if (e < Ecur){
        ed = eb_in[e];
        const unsigned a = (unsigned)(ed >> 16) & 0xFFFFu;
        const unsigned b = (unsigned)ed & 0xFFFFu;
        const unsigned ra = comp[a], rb = comp[b];
        if (ra != rb){
          keep = true;
          const unsigned key = ((((unsigned)(ed >> 32)) + 1u) << 18) | (unsigned)e;
          atomicMax(&bestv[ra], key);
          atomicMax(&bestv[rb], key);
        }
      }
      const unsigned long long bal = __ballot(keep);
      const unsigned cnt = (unsigned)__popcll(bal);
      const unsigned pfx = (unsigned)__popcll(bal & ((1ULL << lane) - 1ULL));
      unsigned wb = 0u;
      if (lane == 0 && cnt) wb = atomicAdd(&ecnt2_s, cnt);
      wb = (unsigned)__shfl((int)wb, 0);
      if (keep && (wb + pfx) < 32768u) eb_out[wb + pfx] = ed;
    }
    __syncthreads();
    for (int t = tid; t < Npk; t += 1024){
      if (comp[t] == (unsigned short)t && bestv[t] != 0u){
        const unsigned long long ed = eb_in[bestv[t] & 0x3FFFFu];
        const unsigned a = (unsigned)(ed >> 16) & 0xFFFFu;
        const unsigned b = (unsigned)ed & 0xFFFFu;
        const unsigned ra = comp[a], rb = comp[b];
        hook[t] = (unsigned short)((ra == (unsigned)t) ? rb : ra);
      }
    }
    __syncthreads();
    for (int t = tid; t < Npk; t += 1024){
      const unsigned o = hook[t];
      if (o != 0xFFFFu && !(hook[o] == (unsigned short)t && (unsigned)t < o)){
        comp[t] = (unsigned short)o;
        chg_s = 1u;
        const unsigned long long ed = eb_in[bestv[t] & 0x3FFFFu];
        const unsigned pos = atomicAdd(&mcnt_s, 1u);
        if (pos < 4096u) msf[pos] = (((ed >> 32) + 1ULL) << 32) | (ed & 0xFFFFFFFFULL);
      }
    }
    __syncthreads();
    for (;;){
      if (tid == 0) flat_s = 0u;
      __syncthreads();
      for (int t = tid; t < Npk; t += 1024){
        const unsigned c = comp[t];
        const unsigned cc = comp[c];
        if (cc != c){ comp[t] = (unsigned short)cc; flat_s = 1u; }
      }
      __syncthreads();
      if (flat_s == 0u) break;
    }
    const int En = ((int)ecnt2_s < 32768) ? (int)ecnt2_s : 32767;
    const unsigned ch = chg_s;
    __syncthreads();
    Ecur = En;
    { unsigned long long* t2 = eb_in; eb_in = eb_out; eb_out = t2; }
    if (ch == 0u) break;
  }

  const int M = ((int)mcnt_s < 4096) ? (int)mcnt_s : 4095;
  int W = 64; while (W < M) W <<= 1;
  for (int t = M + tid; t < W; t += 1024) msf[t] = 0ULL;
  for (int t = tid; t < Npk; t += 1024) comp[t] = (unsigned short)t;
  __syncthreads();
  for (int k = 2; k <= W; k <<= 1){
    for (int j = k >> 1; j > 0; j >>= 1){
      for (int m2 = tid; m2 < W/2; m2 += 1024){
        const int i = ((m2 & ~(j-1)) << 1) | (m2 & (j-1));
        const int p = i | j;
        const bool up = ((i & k) == 0);
        const unsigned long long a = msf[i], b = msf[p];
        if ((a < b) == up){ msf[i] = b; msf[p] = a; }
      }
      __syncthreads();
    }
  }

  {
    const int nb = (M + 63) >> 6;
    for (int bch = 0; bch < nb; ++bch){
      if (tid < 64){
        const int ei = bch*64 + lane;
        unsigned ra = 0xFFFFu, rb = 0xFFFFu, wgt = 0u;
        if (ei < M){
          const unsigned long long e = msf[ei];
          const unsigned a = ((unsigned)e >> 16) & 0xFFFFu;
          const unsigned b = (unsigned)e & 0xFFFFu;
          wgt = (unsigned)(e >> 32) - 1u;
          ra = uf_find2(comp, a);
          rb = uf_find2(comp, b);
        }
        unsigned kra = 0xFFFFu, krb = 0xFFFFu;
        for (int i = 0; i < 64; ++i){
          const unsigned rai = (unsigned)__builtin_amdgcn_readlane((int)ra, i);
          const unsigned rbi = (unsigned)__builtin_amdgcn_readlane((int)rb, i);
          if (rai == 0xFFFFu || rai == rbi) continue;
          if (lane == i){ kra = rai; krb = rbi; }
          ra = (ra == rai) ? rbi : ra;
          rb = (rb == rai) ? rbi : rb;
        }
        if (kra != 0xFFFFu){
          death[pkrank[kra]] = (unsigned short)wgt;
          comp[kra] = (unsigned short)krb;
        }
      }
      __syncthreads();
      for (int t = tid; t < Npk; t += 1024){
        const unsigned c = comp[t];
        const unsigned cc = comp[c];
        if (cc != c) comp[t] = (unsigned short)cc;
      }
      __syncthreads();
    }
  }
  __syncthreads();

  float s = 0.f;
  for (int e = tid; e < NN; e += 1024){
    const int dr = death[e];
    if (dr != 0xFFFF) s += dens[e] - dens[dr];
  }
  red[tid] = s; __syncthreads();
  for (int o = 512; o; o >>= 1){ if (tid < o) red[tid] += red[tid+o]; __syncthreads(); }
  const float S = red[0];

  for (int e8 = 0; e8 < 8; ++e8){
    const int e = tid + e8*1024;
    const int dr = death[e];
    const bool have = (dr != 0xFFFF);
    const unsigned long long bal = __ballot(have);
    const unsigned cnt = (unsigned)__popcll(bal);
    const unsigned pfx = (unsigned)__popcll(bal & ((1ULL << lane) - 1ULL));
    unsigned wb = 0u;
    if (lane == 0 && cnt) wb = atomicAdd(&dcnt_s, cnt);
    wb = (unsigned)__shfl((int)wb, 0);
    if (have && (wb + pfx) < 4096u) dlist[wb + pfx] = ((unsigned)e << 13) | (unsigned)dr;
  }
  __syncthreads();
  const int Dm = ((int)dcnt_s < 4096) ? (int)dcnt_s : 4096;

  unsigned long long last = ~0ULL;
  for (int t10 = 0; t10 < 10; ++t10){
    unsigned long long km = 0ULL;
    for (int i = tid; i < Dm; i += 1024){
      const unsigned pk = dlist[i];
      const unsigned e = pk >> 13, dr = pk & 8191u;
      const float pers = dens[e] - dens[dr];
      const unsigned long long k = (((unsigned long long)__float_as_uint(pers)) << 13) | e;
      if (k < last && k > km) km = k;
    }
    for (int off = 32; off; off >>= 1){
      const unsigned long long o = shfl64_xor(km, off);
      km = (o > km) ? o : km;
    }
    if (lane == 0) wred[tid >> 6] = km;
    __syncthreads();
    if (tid < 64){
      unsigned long long v = (tid < 16) ? wred[tid] : 0ULL;
      for (int off = 8; off; off >>= 1){
        const unsigned long long o = shfl64_xor(v, off);
        v = (o > v) ? o : v;
      }
      if (tid == 0) wred[16] = v;
    }
    __syncthreads();
    const unsigned long long st = wred[16];
    if (tid == 0) sel[t10] = st;
    last = st;
    __syncthreads();
  }
  if (tid == 0){
    float top = 0.f;
    for (int t10 = 0; t10 < 10; ++t10)
      if (sel[t10]) top += __uint_as_float((unsigned)(sel[t10] >> 13));
    float strong = 0.f, dest0 = 0.f, dest1 = 0.f;
    if (sel[0]){
      const unsigned e0 = (unsigned)(sel[0] & 8191ULL);
      dest0 = dens[e0]; dest1 = dens[death[e0]];
    }
    for (int t10 = 1; t10 < 10; ++t10){
      if (!sel[t10]) continue;
      const unsigned e = (unsigned)(sel[t10] & 8191ULL);
      const float a = dens[e] - dest0;
      const float b = dens[death[e]] - dest1;
      strong += sqrtf(a*a + b*b);
    }
    out[0] = (S - top) / 1.41421356237309515f + strong;
  }
}

// =====================================================================
// launch — 5 dispatches
// =====================================================================
extern "C" void kernel_launch(void* const* d_in, const int* in_sizes, int n_in,
                              void* d_out, int out_size, void* d_ws, size_t ws_size,
                              hipStream_t stream){
  const float* x = (const float*)d_in[0];
  char* w = (char*)d_ws;
  float*          sq     = (float*)(w + 0);                 // 32KB
  float*          res    = (float*)(w + 32768);             // 32KB
  float*          dens_s = (float*)(w + 65536);             // 32KB
  unsigned short* rank   = (unsigned short*)(w + 98304);    // 16KB
  unsigned short* nn16   = (unsigned short*)(w + 114688);   // 256KB
  unsigned short* ups_t  = (unsigned short*)(w + 376832);   // 256KB (edge ping-pong in B2)
  float*          xT     = (float*)(w + 655360);            // 2MB (optional)
  const int use_xt = (ws_size >= (size_t)(655360 + NN*DD*4)) ? 1 : 0;
  unsigned long long* edges = use_xt ? (unsigned long long*)(w + 655360)
                                     : (unsigned long long*)(w + 114688);
  const int edgecap = use_xt ? 262143 : 32767;

  k_pre<<<128, 256, 0, stream>>>(x, xT, sq, use_xt);
  if (use_xt) k_cand<true ><<<1024, 256, 0, stream>>>(x, xT, sq, res, nn16);
  else        k_cand<false><<<1024, 256, 0, stream>>>(x, xT, sq, res, nn16);
  k_rank<<<64, 256, 0, stream>>>(res, rank, dens_s);
  k_ups <<<32, 256, 0, stream>>>(rank, nn16, ups_t);
  k_msf <<<1, 1024, 0, stream>>>(dens_s, ups_t, edges, edgecap, (float*)d_out);
}